// Round 5
// baseline (405.872 us; speedup 1.0000x reference)
//
#include <hip/hip_runtime.h>
#include <hip/hip_bf16.h>
#include <cstdint>
#include <cstddef>

static constexpr int T_TOK = 8192;   // B*S
static constexpr int D_DIM = 768;
static constexpr int E_NUM = 8;
static constexpr int F_DIM = 3072;
static constexpr int MAX_TILES = 72; // sum ceil(cnt/128) <= 71; 9 per XCD x 8

typedef __attribute__((ext_vector_type(8))) short short8;
typedef __attribute__((ext_vector_type(16))) float floatx16;
typedef __attribute__((ext_vector_type(8))) unsigned short ushort8v;

__device__ __forceinline__ void async16(const void* g, void* l) {
  __builtin_amdgcn_global_load_lds(
      (const __attribute__((address_space(1))) unsigned int*)g,
      (__attribute__((address_space(3))) unsigned int*)l, 16, 0, 0);
}

// gelu tanh-approx in sigmoid form: x*sigmoid(1.59577x + 0.0713548x^3)
// max dev vs exact erf-gelu ~3e-4 (absmax headroom 4.8x)
__device__ __forceinline__ float gelu_fast(float v) {
  float s = v * (1.5957691f + 0.071354813f * v * v);
  return v / (1.0f + __expf(-s));
}

// ---------------- gate: logits fp32, argmax, fused x->bf16. NO atomics. ------
__global__ __launch_bounds__(256)
void gate_kernel(const float* __restrict__ x, const float* __restrict__ gw,
                 const float* __restrict__ gb, int* __restrict__ expert_idx,
                 __hip_bfloat16* __restrict__ xb) {
  int gid = blockIdx.x * blockDim.x + threadIdx.x;
  int tok = gid >> 6;
  int lane = threadIdx.x & 63;
  if (tok >= T_TOK) return;
  const float* xr = x + (size_t)tok * D_DIM;
  __hip_bfloat16* xbr = xb + (size_t)tok * D_DIM;
  float acc[8];
#pragma unroll
  for (int e = 0; e < 8; e++) acc[e] = 0.f;
#pragma unroll
  for (int i = 0; i < D_DIM / 64; i++) {
    int d = lane + i * 64;
    float v = xr[d];
    xbr[d] = __float2bfloat16(v);
    const float4* g4 = (const float4*)(gw + (size_t)d * 8);
    float4 a = g4[0], b = g4[1];
    acc[0] += v * a.x; acc[1] += v * a.y; acc[2] += v * a.z; acc[3] += v * a.w;
    acc[4] += v * b.x; acc[5] += v * b.y; acc[6] += v * b.z; acc[7] += v * b.w;
  }
#pragma unroll
  for (int e = 0; e < 8; e++) {
#pragma unroll
    for (int o = 32; o > 0; o >>= 1) acc[e] += __shfl_xor(acc[e], o, 64);
  }
  if (lane == 0) {
    int best = 0;
    float bv = acc[0] + gb[0];
#pragma unroll
    for (int e = 1; e < 8; e++) {
      float v = acc[e] + gb[e];
      if (v > bv) { bv = v; best = e; }  // strict > == np.argmax tie-break
    }
    expert_idx[tok] = best;
  }
}

// ---------------- count: LDS histogram, 8 global atomics per block ----------
__global__ __launch_bounds__(256)
void count_kernel(const int* __restrict__ expert_idx, int* __restrict__ counts) {
  __shared__ int h[E_NUM];
  if (threadIdx.x < E_NUM) h[threadIdx.x] = 0;
  __syncthreads();
  int t = blockIdx.x * blockDim.x + threadIdx.x;
  if (t < T_TOK) atomicAdd(&h[expert_idx[t]], 1);
  __syncthreads();
  if (threadIdx.x < E_NUM && h[threadIdx.x] > 0)
    atomicAdd(&counts[threadIdx.x], h[threadIdx.x]);
}

// ---------------- offsets + compact tile table ----------------
__global__ void offsets_kernel(const int* __restrict__ counts, int* __restrict__ offs,
                               int* __restrict__ meta) {
  if (threadIdx.x == 0) {
    int s = 0, tc = 0;
    for (int e = 0; e < E_NUM; e++) {
      offs[e] = s;
      int cnt = counts[e];
      for (int m = 0; m * 128 < cnt; m++) {
        meta[1 + tc] = e;
        meta[1 + MAX_TILES + tc] = m;
        tc++;
      }
      s += cnt;
    }
    offs[E_NUM] = s;
    meta[0] = tc;
  }
}

// ---------------- scatter: LDS ranks + block-aggregated global base --------
__global__ __launch_bounds__(256)
void scatter_kernel(const int* __restrict__ expert_idx, const int* __restrict__ offs,
                    int* __restrict__ fill, int* __restrict__ perm) {
  __shared__ int lcnt[E_NUM];
  __shared__ int lbase[E_NUM];
  if (threadIdx.x < E_NUM) lcnt[threadIdx.x] = 0;
  __syncthreads();
  int t = blockIdx.x * blockDim.x + threadIdx.x;
  int e = -1, rank = 0;
  if (t < T_TOK) {
    e = expert_idx[t];
    rank = atomicAdd(&lcnt[e], 1);   // LDS atomic: per-CU, cheap
  }
  __syncthreads();
  if (threadIdx.x < E_NUM)
    lbase[threadIdx.x] = (lcnt[threadIdx.x] > 0)
                           ? atomicAdd(&fill[threadIdx.x], lcnt[threadIdx.x]) : 0;
  __syncthreads();
  if (t < T_TOK) perm[offs[e] + lbase[e] + rank] = t;
}

// ---------------- weight transpose + cast: in [R][C] fp32 -> out [C][R] bf16 ----
__global__ __launch_bounds__(256)
void transpose_bf16(const float* __restrict__ in, __hip_bfloat16* __restrict__ out,
                    int R, int C) {
  __shared__ float t[64][65];
  const float* src = in + (size_t)blockIdx.z * R * C;
  __hip_bfloat16* dst = out + (size_t)blockIdx.z * R * C;
  int r0 = blockIdx.y * 64, c0 = blockIdx.x * 64;
  int tx = threadIdx.x & 15;
  int ty = threadIdx.x >> 4;
#pragma unroll
  for (int p = 0; p < 4; p++) {
    int r = ty + p * 16;
    float4 v = *(const float4*)&src[(size_t)(r0 + r) * C + c0 + tx * 4];
    t[tx * 4 + 0][r] = v.x; t[tx * 4 + 1][r] = v.y;
    t[tx * 4 + 2][r] = v.z; t[tx * 4 + 3][r] = v.w;
  }
  __syncthreads();
  int j = threadIdx.x & 7;
#pragma unroll
  for (int p = 0; p < 2; p++) {
    int cc = (threadIdx.x >> 3) + p * 32;
    __align__(16) __hip_bfloat16 tmp[8];
#pragma unroll
    for (int i = 0; i < 8; i++) tmp[i] = __float2bfloat16(t[cc][j * 8 + i]);
    *(ushort8v*)&dst[(size_t)(c0 + cc) * R + r0 + j * 8] = *(const ushort8v*)tmp;
  }
}

// ---------------- GEMM1: H[perm-order] = gelu(xb_gathered @ w1t^T + b1) ----------
// 128x64 tile, BK=64 (two swizzled BK=32 sub-tiles), 32x32x16 MFMA,
// wave = 32 rows x 64 cols (acc 2x f32x16 = 32 VGPR), 4 blocks/CU target.
__global__ __launch_bounds__(256, 4)
void moe_gemm1(const __hip_bfloat16* __restrict__ A,   // xb [T][D]
               const __hip_bfloat16* __restrict__ Bt,  // w1t [E][F][D]
               const float* __restrict__ bias,         // b1 [E][F]
               const int* __restrict__ meta,
               const int* __restrict__ offs,
               const int* __restrict__ perm,
               __hip_bfloat16* __restrict__ H) {
  constexpr int K = D_DIM, N = F_DIM;
  int g = blockIdx.x;
  int xcd = g & 7;
  int j = g >> 3;
  int mt = (j % 9) * 8 + xcd;   // balanced: XCDs get ceil/floor(n_tiles/8) each
  int nt = j / 9;               // 0..47
  if (mt >= meta[0]) return;
  int e = meta[1 + mt];
  int m0 = meta[1 + MAX_TILES + mt] * 128;
  int off = offs[e], cnt = offs[e + 1] - off;
  int n0 = nt * 64;

  __shared__ __align__(16) __hip_bfloat16 As[2 * 128 * 32];  // 16 KB
  __shared__ __align__(16) __hip_bfloat16 Bs[2 * 64 * 32];   //  8 KB

  int tid = threadIdx.x, lane = tid & 63, w = tid >> 6;
  // staging: A rows w*32..+31 (two async16), B rows w*16..+15 (one async16)
  int lr0 = w * 32 + (lane >> 2), lr1 = lr0 + 16;
  int ch = (lane & 3) ^ ((lane >> 3) & 3);

  int r0 = m0 + lr0; if (r0 > cnt - 1) r0 = cnt - 1;
  int r1 = m0 + lr1; if (r1 > cnt - 1) r1 = cnt - 1;
  const __hip_bfloat16* a0 = A + (size_t)perm[off + r0] * K + ch * 8;
  const __hip_bfloat16* a1 = A + (size_t)perm[off + r1] * K + ch * 8;
  int brow = w * 16 + (lane >> 2);
  const __hip_bfloat16* bp = Bt + ((size_t)e * N + n0 + brow) * K + ch * 8;

  // fragment offsets: A row = w*32 + (lane&31); k-chunk = kstep*2 + (lane>>5)
  int q = lane >> 5;
  int row_a = w * 32 + (lane & 31);
  int aoff[2], boff[2][2];
#pragma unroll
  for (int kst = 0; kst < 2; kst++) {
    int c = kst * 2 + q;
    aoff[kst] = row_a * 32 + ((c ^ ((row_a >> 1) & 3)) * 8);
#pragma unroll
    for (int ni = 0; ni < 2; ni++) {
      int row_b = ni * 32 + (lane & 31);
      boff[ni][kst] = row_b * 32 + ((c ^ ((row_b >> 1) & 3)) * 8);
    }
  }

  floatx16 acc[2];
#pragma unroll
  for (int ni = 0; ni < 2; ni++)
#pragma unroll
    for (int i = 0; i < 16; i++) acc[ni][i] = 0.f;

  for (int kk = 0; kk < K; kk += 64) {
    __syncthreads();
#pragma unroll
    for (int ks = 0; ks < 2; ks++) {
      int ko = kk + ks * 32;
      async16(a0 + ko, &As[ks * 4096 + (w * 32) * 32]);
      async16(a1 + ko, &As[ks * 4096 + (w * 32 + 16) * 32]);
      async16(bp + ko, &Bs[ks * 2048 + (w * 16) * 32]);
    }
    __syncthreads();
#pragma unroll
    for (int ks = 0; ks < 2; ks++) {
#pragma unroll
      for (int kst = 0; kst < 2; kst++) {
        short8 af = *(const short8*)&As[ks * 4096 + aoff[kst]];
#pragma unroll
        for (int ni = 0; ni < 2; ni++) {
          short8 bf = *(const short8*)&Bs[ks * 2048 + boff[ni][kst]];
          acc[ni] = __builtin_amdgcn_mfma_f32_32x32x16_bf16(af, bf, acc[ni], 0, 0, 0);
        }
      }
    }
  }

  // epilogue: C/D 32x32 layout col=lane&31, row=(reg&3)+8*(reg>>2)+4*(lane>>5)
  int gmr[16];
#pragma unroll
  for (int reg = 0; reg < 16; reg++)
    gmr[reg] = m0 + w * 32 + (reg & 3) + 8 * (reg >> 2) + 4 * q;
#pragma unroll
  for (int ni = 0; ni < 2; ni++) {
    int col = n0 + ni * 32 + (lane & 31);
    float bia = bias[(size_t)e * N + col];
#pragma unroll
    for (int reg = 0; reg < 16; reg++) {
      if (gmr[reg] < cnt)
        H[(size_t)(off + gmr[reg]) * N + col] =
            __float2bfloat16(gelu_fast(acc[ni][reg] + bia));
    }
  }
}

// ---------------- GEMM2: out[perm] = H @ w2t^T + b2, 128x64, 32x32x16 ----------
__global__ __launch_bounds__(256, 4)
void moe_gemm2(const __hip_bfloat16* __restrict__ A,   // H [T][F] (permuted rows)
               const __hip_bfloat16* __restrict__ Bt,  // w2t [E][D][F]
               const float* __restrict__ bias,         // b2 [E][D]
               const int* __restrict__ meta,
               const int* __restrict__ offs,
               const int* __restrict__ perm,
               float* __restrict__ Out) {
  constexpr int K = F_DIM, N = D_DIM;
  int g = blockIdx.x;
  int xcd = g & 7;
  int j = g >> 3;
  int mt = (j % 9) * 8 + xcd;
  int nt = j / 9;               // 0..11
  if (mt >= meta[0]) return;
  int e = meta[1 + mt];
  int m0 = meta[1 + MAX_TILES + mt] * 128;
  int off = offs[e], cnt = offs[e + 1] - off;
  int n0 = nt * 64;

  __shared__ __align__(16) __hip_bfloat16 As[2 * 128 * 32];
  __shared__ __align__(16) __hip_bfloat16 Bs[2 * 64 * 32];

  int tid = threadIdx.x, lane = tid & 63, w = tid >> 6;
  int lr0 = w * 32 + (lane >> 2), lr1 = lr0 + 16;
  int ch = (lane & 3) ^ ((lane >> 3) & 3);

  int r0 = m0 + lr0; if (r0 > cnt - 1) r0 = cnt - 1;
  int r1 = m0 + lr1; if (r1 > cnt - 1) r1 = cnt - 1;
  const __hip_bfloat16* a0 = A + (size_t)(off + r0) * K + ch * 8;
  const __hip_bfloat16* a1 = A + (size_t)(off + r1) * K + ch * 8;
  int brow = w * 16 + (lane >> 2);
  const __hip_bfloat16* bp = Bt + ((size_t)e * N + n0 + brow) * K + ch * 8;

  int q = lane >> 5;
  int row_a = w * 32 + (lane & 31);
  int aoff[2], boff[2][2];
#pragma unroll
  for (int kst = 0; kst < 2; kst++) {
    int c = kst * 2 + q;
    aoff[kst] = row_a * 32 + ((c ^ ((row_a >> 1) & 3)) * 8);
#pragma unroll
    for (int ni = 0; ni < 2; ni++) {
      int row_b = ni * 32 + (lane & 31);
      boff[ni][kst] = row_b * 32 + ((c ^ ((row_b >> 1) & 3)) * 8);
    }
  }

  floatx16 acc[2];
#pragma unroll
  for (int ni = 0; ni < 2; ni++)
#pragma unroll
    for (int i = 0; i < 16; i++) acc[ni][i] = 0.f;

  for (int kk = 0; kk < K; kk += 64) {
    __syncthreads();
#pragma unroll
    for (int ks = 0; ks < 2; ks++) {
      int ko = kk + ks * 32;
      async16(a0 + ko, &As[ks * 4096 + (w * 32) * 32]);
      async16(a1 + ko, &As[ks * 4096 + (w * 32 + 16) * 32]);
      async16(bp + ko, &Bs[ks * 2048 + (w * 16) * 32]);
    }
    __syncthreads();
#pragma unroll
    for (int ks = 0; ks < 2; ks++) {
#pragma unroll
      for (int kst = 0; kst < 2; kst++) {
        short8 af = *(const short8*)&As[ks * 4096 + aoff[kst]];
#pragma unroll
        for (int ni = 0; ni < 2; ni++) {
          short8 bf = *(const short8*)&Bs[ks * 2048 + boff[ni][kst]];
          acc[ni] = __builtin_amdgcn_mfma_f32_32x32x16_bf16(af, bf, acc[ni], 0, 0, 0);
        }
      }
    }
  }

  int dst[16];
#pragma unroll
  for (int reg = 0; reg < 16; reg++) {
    int gm = m0 + w * 32 + (reg & 3) + 8 * (reg >> 2) + 4 * q;
    dst[reg] = (gm < cnt) ? perm[off + gm] : -1;
  }
#pragma unroll
  for (int ni = 0; ni < 2; ni++) {
    int col = n0 + ni * 32 + (lane & 31);
    float bia = bias[(size_t)e * N + col];
#pragma unroll
    for (int reg = 0; reg < 16; reg++) {
      if (dst[reg] >= 0)
        Out[(size_t)dst[reg] * N + col] = acc[ni][reg] + bia;
    }
  }
}

extern "C" void kernel_launch(void* const* d_in, const int* in_sizes, int n_in,
                              void* d_out, int out_size, void* d_ws, size_t ws_size,
                              hipStream_t stream) {
  const float* x  = (const float*)d_in[0];
  const float* gw = (const float*)d_in[1];
  const float* gb = (const float*)d_in[2];
  const float* w1 = (const float*)d_in[3];
  const float* b1 = (const float*)d_in[4];
  const float* w2 = (const float*)d_in[5];
  const float* b2 = (const float*)d_in[6];
  float* out = (float*)d_out;

  char* ws = (char*)d_ws;
  int* counts = (int*)(ws + 0);
  int* fill   = (int*)(ws + 32);
  int* offs   = (int*)(ws + 64);
  int* meta   = (int*)(ws + 128);   // 145 ints
  int* eidx   = (int*)(ws + 1024);
  int* perm   = (int*)(ws + 1024 + 4 * T_TOK);
  size_t off = 1024 + 8 * (size_t)T_TOK;
  __hip_bfloat16* xb  = (__hip_bfloat16*)(ws + off); off += (size_t)T_TOK * D_DIM * 2;
  __hip_bfloat16* w1t = (__hip_bfloat16*)(ws + off); off += (size_t)E_NUM * D_DIM * F_DIM * 2;
  __hip_bfloat16* w2t = (__hip_bfloat16*)(ws + off); off += (size_t)E_NUM * D_DIM * F_DIM * 2;
  __hip_bfloat16* H   = (__hip_bfloat16*)(ws + off); off += (size_t)T_TOK * F_DIM * 2;

  hipMemsetAsync(d_ws, 0, 64, stream);  // counts + fill
  gate_kernel<<<T_TOK / 4, 256, 0, stream>>>(x, gw, gb, eidx, xb);
  count_kernel<<<T_TOK / 256, 256, 0, stream>>>(eidx, counts);
  offsets_kernel<<<1, 64, 0, stream>>>(counts, offs, meta);
  scatter_kernel<<<T_TOK / 256, 256, 0, stream>>>(eidx, offs, fill, perm);
  transpose_bf16<<<dim3(F_DIM / 64, D_DIM / 64, E_NUM), 256, 0, stream>>>(w1, w1t, D_DIM, F_DIM);
  transpose_bf16<<<dim3(D_DIM / 64, F_DIM / 64, E_NUM), 256, 0, stream>>>(w2, w2t, F_DIM, D_DIM);
  moe_gemm1<<<8 * 9 * (F_DIM / 64), 256, 0, stream>>>(xb, w1t, b1, meta, offs, perm, H);
  moe_gemm2<<<8 * 9 * (D_DIM / 64), 256, 0, stream>>>(H, w2t, b2, meta, offs, perm, out);
}